// Round 2
// baseline (1865.808 us; speedup 1.0000x reference)
//
#include <hip/hip_runtime.h>
#include <stdint.h>

typedef __bf16 bf16;
typedef __attribute__((ext_vector_type(8))) __bf16 bf16x8;
typedef __attribute__((ext_vector_type(4))) float floatx4;

__device__ inline float bflo(uint32_t u){ union{uint32_t v; float f;} t; t.v = u << 16; return t.f; }
__device__ inline float bfhi(uint32_t u){ union{uint32_t v; float f;} t; t.v = u & 0xffff0000u; return t.f; }
__device__ inline uint32_t pack2(float a, float b){ union{ bf16 h[2]; uint32_t u; } t; t.h[0]=(bf16)a; t.h[1]=(bf16)b; return t.u; }

__device__ inline void load4(const bf16* p, float* x){
  uint2 u = *(const uint2*)p; x[0]=bflo(u.x); x[1]=bfhi(u.x); x[2]=bflo(u.y); x[3]=bfhi(u.y);
}
__device__ inline void load4(const float* p, float* x){
  float4 u = *(const float4*)p; x[0]=u.x; x[1]=u.y; x[2]=u.z; x[3]=u.w;
}

// async global->LDS, 16B per lane (dest must be wave-uniform base + lane*16)
__device__ inline void gload16(const void* g, void* l){
  __builtin_amdgcn_global_load_lds((const __attribute__((address_space(1))) uint32_t*)g,
                                   (__attribute__((address_space(3))) uint32_t*)l, 16, 0, 0);
}

// ---------------- f32 -> bf16 weight conversion (once per launch; amortized over tile-row re-reads) ----------------
__global__ __launch_bounds__(256) void cvt_kernel(const float* __restrict__ in, bf16* __restrict__ out, int n8)
{
  int i = blockIdx.x * 256 + threadIdx.x;
  if (i >= n8) return;
  const float* p = in + (size_t)i * 8;
  float4 a = *(const float4*)p;
  float4 b = *(const float4*)(p + 4);
  union{ uint4 q; bf16 h[8]; } pk;
  pk.h[0]=(bf16)a.x; pk.h[1]=(bf16)a.y; pk.h[2]=(bf16)a.z; pk.h[3]=(bf16)a.w;
  pk.h[4]=(bf16)b.x; pk.h[5]=(bf16)b.y; pk.h[6]=(bf16)b.z; pk.h[7]=(bf16)b.w;
  *(uint4*)(out + (size_t)i*8) = pk.q;
}

// ---------------- LayerNorm (row-per-block, width W). In-place safe (row loaded to regs first). ----------------
template<int W, typename TIN>
__global__ __launch_bounds__(256) void ln_kernel(const TIN* in, const float* __restrict__ g,
                                                 const float* __restrict__ bb, bf16* out, int M)
{
  constexpr int E = W / 256;
  int row = blockIdx.x; if (row >= M) return;
  int tid = threadIdx.x;
  const TIN* rp = in + (size_t)row * W + tid * E;
  float x[E];
  #pragma unroll
  for (int j = 0; j < E; j += 4) load4(rp + j, &x[j]);
  float s = 0.f, ss = 0.f;
  #pragma unroll
  for (int e = 0; e < E; e++){ s += x[e]; ss += x[e]*x[e]; }
  #pragma unroll
  for (int k = 32; k >= 1; k >>= 1){ s += __shfl_xor(s, k, 64); ss += __shfl_xor(ss, k, 64); }
  __shared__ float rs_[4], rq_[4];
  if ((tid & 63) == 0){ rs_[tid >> 6] = s; rq_[tid >> 6] = ss; }
  __syncthreads();
  s = rs_[0]+rs_[1]+rs_[2]+rs_[3]; ss = rq_[0]+rq_[1]+rq_[2]+rq_[3];
  float mean = s * (1.0f / W);
  float var  = ss * (1.0f / W) - mean * mean;
  float rinv = rsqrtf(var + 1e-5f);
  bf16* op = out + (size_t)row * W + tid * E;
  const float* gp = g + tid * E;
  const float* bp = bb + tid * E;
  #pragma unroll
  for (int j = 0; j < E; j += 4){
    float gv[4], bv[4];
    load4(gp + j, gv); load4(bp + j, bv);
    float y0 = (x[j]  -mean)*rinv*gv[0] + bv[0];
    float y1 = (x[j+1]-mean)*rinv*gv[1] + bv[1];
    float y2 = (x[j+2]-mean)*rinv*gv[2] + bv[2];
    float y3 = (x[j+3]-mean)*rinv*gv[3] + bv[3];
    uint2 o; o.x = pack2(y0, y1); o.y = pack2(y2, y3);
    *(uint2*)(op + j) = o;
  }
}

// ---------------- NT GEMM: C[M,N] = A[M,K](bf16) @ B[N,K]^T(bf16) + bias(f32), fused epilogues ----------------
// mode 0: +bias ; mode 1: +bias+extra[m,n] ; mode 2: silu(extra[m,n]) * (acc+bias)   [extra may alias C]
// m97 structure: 128x128 tile, BK=32, global_load_lds width-16 staging, stage(k+1) issued before MFMA(k).
template<typename TE, typename TC>
__global__ __launch_bounds__(256) void gemm_bt(const bf16* __restrict__ A, const bf16* __restrict__ Bw,
                                               const float* __restrict__ bias, const TE* extra,
                                               TC* C, int M, int N, int K, int mode)
{
  __shared__ __align__(16) bf16 As[128*32];
  __shared__ __align__(16) bf16 Bs[128*32];
  int tid = threadIdx.x;
  int lane = tid & 63, wave = tid >> 6;
  int l16 = lane & 15, quad = lane >> 4;
  int wm = wave >> 1, wn = wave & 1;
  int m0 = blockIdx.y * 128, n0 = blockIdx.x * 128;
  floatx4 acc[4][4];
  #pragma unroll
  for (int i = 0; i < 4; i++)
    #pragma unroll
    for (int j = 0; j < 4; j++) acc[i][j] = (floatx4){0.f,0.f,0.f,0.f};
  int nk = K >> 5;

  // Staging geometry: tile is 128 rows x 32 cols bf16 = 8192 B; 256 threads x 16 B = 4096 B
  // per issue -> 2 issues per operand. LDS written LINEARLY (tid*16 B) == row-major [row][32]
  // with row = lin>>2, col = (lin&3)*8  (global_load_lds wave-uniform-dest constraint).
  int rowS = tid >> 2;            // 0..63 within each 64-row half
  int colS = (tid & 3) * 8;
  int ra0 = min(m0 + rowS,      M-1);
  int ra1 = min(m0 + 64 + rowS, M-1);
  int rb0 = min(n0 + rowS,      N-1);
  int rb1 = min(n0 + 64 + rowS, N-1);
  const bf16* pa0 = A  + (size_t)ra0 * K + colS;
  const bf16* pa1 = A  + (size_t)ra1 * K + colS;
  const bf16* pb0 = Bw + (size_t)rb0 * K + colS;
  const bf16* pb1 = Bw + (size_t)rb1 * K + colS;
  bf16* la0 = &As[tid*8];        bf16* la1 = &As[2048 + tid*8];
  bf16* lb0 = &Bs[tid*8];        bf16* lb1 = &Bs[2048 + tid*8];
  auto stage = [&](int kt){
    int ko = kt * 32;
    gload16(pa0 + ko, la0);
    gload16(pa1 + ko, la1);
    gload16(pb0 + ko, lb0);
    gload16(pb1 + ko, lb1);
  };

  stage(0);
  int kt = 0;
  while (true){
    __syncthreads();             // drains vmcnt(0): tile kt resident in LDS
    bf16x8 af[4], bfv[4];
    #pragma unroll
    for (int i = 0; i < 4; i++) af[i]  = *(const bf16x8*)&As[(wm*64 + i*16 + l16)*32 + quad*8];
    #pragma unroll
    for (int j = 0; j < 4; j++) bfv[j] = *(const bf16x8*)&Bs[(wn*64 + j*16 + l16)*32 + quad*8];
    ++kt;
    bool more = kt < nk;
    if (more){
      __syncthreads();           // all waves' frag reads done before overwrite
      stage(kt);                 // async loads fly under the MFMA block below
    }
    #pragma unroll
    for (int i = 0; i < 4; i++)
      #pragma unroll
      for (int j = 0; j < 4; j++)
        acc[i][j] = __builtin_amdgcn_mfma_f32_16x16x32_bf16(af[i], bfv[j], acc[i][j], 0, 0, 0);
    if (!more) break;
  }

  #pragma unroll
  for (int i = 0; i < 4; i++){
    int gmb = m0 + wm*64 + i*16 + quad*4;
    #pragma unroll
    for (int j = 0; j < 4; j++){
      int gn = n0 + wn*64 + j*16 + l16;
      float bv = bias ? bias[gn] : 0.f;
      #pragma unroll
      for (int r = 0; r < 4; r++){
        int gm = gmb + r;
        if (gm < M){
          float v = acc[i][j][r] + bv;
          if (mode == 1) v += (float)extra[(size_t)gm * N + gn];
          else if (mode == 2){ float a = (float)extra[(size_t)gm * N + gn]; v *= a / (1.f + __expf(-a)); }
          C[(size_t)gm * N + gn] = (TC)v;
        }
      }
    }
  }
}

// ---------------- RoPE (in-place on q and k buffers (bf16), tokens 1..256, all dims) ----------------
__global__ __launch_bounds__(256) void rope_kernel(bf16* __restrict__ q, bf16* __restrict__ k,
                                                   const float* __restrict__ cs, const float* __restrict__ sn)
{
  uint32_t i = blockIdx.x * 256u + threadIdx.x;   // 64*256*512 pairs
  int d0 = (int)(i & 511) * 2;
  int tok = (int)((i >> 9) & 255);
  int b = (int)(i >> 17);
  int j = d0 & 63;                                // dim within 64-wide head
  float c0 = cs[tok*64 + j], c1 = cs[tok*64 + j + 1];
  float s0 = sn[tok*64 + j], s1 = sn[tok*64 + j + 1];
  size_t off = ((size_t)(b*257 + tok + 1)) * 1024 + d0;
  uint32_t uq = *(const uint32_t*)(q + off);
  float x0 = bflo(uq), x1 = bfhi(uq);
  *(uint32_t*)(q + off) = pack2(x0*c0 - x1*s0, x1*c1 + x0*s1);
  uint32_t uk = *(const uint32_t*)(k + off);
  float y0 = bflo(uk), y1 = bfhi(uk);
  *(uint32_t*)(k + off) = pack2(y0*c0 - y1*s0, y1*c1 + y0*s1);
}

// ---------------- attention: one block per (b,h,qtile); flash-style over 2 KV chunks of 144 ----------------
__global__ __launch_bounds__(256) void attn_kernel(const bf16* __restrict__ Q, const bf16* __restrict__ Kg,
                                                   const bf16* __restrict__ Vg, const float* __restrict__ tab,
                                                   bf16* __restrict__ AO)
{
  __shared__ __align__(16) bf16 Kc[144*64];      // 18432 B
  __shared__ __align__(16) bf16 Vt[64*160];      // 20480 B  (V^T chunk, tok padded to 160)
  __shared__ __align__(16) float S[16*160];      // 10240 B
  __shared__ __align__(16) bf16 P[16*160];       //  5120 B
  __shared__ float mrow[16], lrow[16], arow[16];
  int id = blockIdx.x;
  int qt = id % 17; int rest = id / 17;
  int h = rest & 15; int b = rest >> 4;
  int tid = threadIdx.x; int wave = tid >> 6; int lane = tid & 63;
  int l16 = lane & 15, quad = lane >> 4;
  size_t base = ((size_t)b * 257) * 1024 + h * 64;
  int q0 = qt * 16;
  int tokA = min(q0 + l16, 256);
  const bf16* qp = Q + base + (size_t)tokA * 1024;
  bf16x8 a0 = *(const bf16x8*)(qp + quad*8);
  bf16x8 a1 = *(const bf16x8*)(qp + 32 + quad*8);
  floatx4 o = (floatx4){0.f,0.f,0.f,0.f};
  if (tid < 16){ mrow[tid] = -1e30f; lrow[tid] = 0.f; }
  for (int ch = 0; ch < 2; ch++){
    int t0 = ch * 144;
    __syncthreads();   // previous PV done (and init visible) before restaging
    for (int i = tid; i < 144*8; i += 256){
      int row = i >> 3, c8 = (i & 7) * 8;
      int tok = t0 + row;
      uint4 u = make_uint4(0,0,0,0);
      if (tok <= 256) u = *(const uint4*)(Kg + base + (size_t)tok*1024 + c8);
      *(uint4*)&Kc[row*64 + c8] = u;
    }
    for (int i = tid; i < 160*8; i += 256){
      int trow = i >> 3, c8 = (i & 7) * 8;
      int tok = t0 + trow;
      uint4 u = make_uint4(0,0,0,0);
      if (trow < 144 && tok <= 256) u = *(const uint4*)(Vg + base + (size_t)tok*1024 + c8);
      union { uint4 q4; bf16 h8[8]; } tmp; tmp.q4 = u;
      #pragma unroll
      for (int jj = 0; jj < 8; jj++) Vt[(c8 + jj)*160 + trow] = tmp.h8[jj];
    }
    __syncthreads();
    // S = Qtile @ Kc^T  (waves split over 9 kv sub-tiles)
    for (int nt = wave; nt < 9; nt += 4){
      int kr = nt*16 + l16;
      bf16x8 b0 = *(const bf16x8*)&Kc[kr*64 + quad*8];
      bf16x8 b1 = *(const bf16x8*)&Kc[kr*64 + 32 + quad*8];
      floatx4 c = (floatx4){0.f,0.f,0.f,0.f};
      c = __builtin_amdgcn_mfma_f32_16x16x32_bf16(a0, b0, c, 0, 0, 0);
      c = __builtin_amdgcn_mfma_f32_16x16x32_bf16(a1, b1, c, 0, 0, 0);
      #pragma unroll
      for (int r = 0; r < 4; r++) S[(quad*4 + r)*160 + nt*16 + l16] = c[r];
    }
    __syncthreads();
    // online softmax partial (16 threads per q row)
    {
      int r = tid >> 4, li = tid & 15;
      int qg = q0 + r; bool vrow = qg <= 256;
      float vals[10]; float mc = -1e30f;
      #pragma unroll
      for (int jj = 0; jj < 10; jj++){
        int c = li + 16*jj; int kg = t0 + c;
        float sv = -1e30f;
        if (vrow && c < 144 && kg <= 256){
          int idx;
          if (qg == 0 && kg == 0) idx = 963;
          else if (qg == 0) idx = 961;
          else if (kg == 0) idx = 962;
          else { int p = qg - 1, pk = kg - 1;
                 idx = ((p >> 4) - (pk >> 4) + 15) * 31 + ((p & 15) - (pk & 15) + 15); }
          sv = S[r*160 + c] * 0.125f + tab[idx*16 + h];
        }
        vals[jj] = sv; mc = fmaxf(mc, sv);
      }
      #pragma unroll
      for (int k = 8; k >= 1; k >>= 1) mc = fmaxf(mc, __shfl_xor(mc, k, 16));
      float mold = mrow[r];
      float mnew = fmaxf(mold, mc);
      float alpha = __expf(mold - mnew);
      float sum = 0.f;
      #pragma unroll
      for (int jj = 0; jj < 10; jj++){
        float p = (vals[jj] > -1e29f) ? __expf(vals[jj] - mnew) : 0.f;
        sum += p;
        P[r*160 + li + 16*jj] = (bf16)p;
      }
      #pragma unroll
      for (int k = 8; k >= 1; k >>= 1) sum += __shfl_xor(sum, k, 16);
      if (li == 0){ mrow[r] = mnew; lrow[r] = lrow[r]*alpha + sum; arow[r] = alpha; }
    }
    __syncthreads();
    // rescale + PV
    #pragma unroll
    for (int r2 = 0; r2 < 4; r2++) o[r2] *= arow[quad*4 + r2];
    #pragma unroll
    for (int ks = 0; ks < 5; ks++){
      bf16x8 pa = *(const bf16x8*)&P[l16*160 + ks*32 + quad*8];
      bf16x8 vb = *(const bf16x8*)&Vt[(wave*16 + l16)*160 + ks*32 + quad*8];
      o = __builtin_amdgcn_mfma_f32_16x16x32_bf16(pa, vb, o, 0, 0, 0);
    }
  }
  #pragma unroll
  for (int r2 = 0; r2 < 4; r2++){
    int qr = q0 + quad*4 + r2;
    if (qr <= 256){
      float inv = 1.0f / lrow[quad*4 + r2];
      AO[base + (size_t)qr*1024 + wave*16 + l16] = (bf16)(o[r2] * inv);
    }
  }
}

extern "C" void kernel_launch(void* const* d_in, const int* in_sizes, int n_in,
                              void* d_out, int out_size, void* d_ws, size_t ws_size,
                              hipStream_t stream)
{
  (void)in_sizes; (void)n_in; (void)out_size; (void)ws_size;
  const float* x    = (const float*)d_in[0];
  const float* rc   = (const float*)d_in[1];
  const float* rsn  = (const float*)d_in[2];
  const float* q_w  = (const float*)d_in[3];
  const float* q_b  = (const float*)d_in[4];
  const float* k_w  = (const float*)d_in[5];
  const float* v_w  = (const float*)d_in[6];
  const float* v_b  = (const float*)d_in[7];
  const float* tab  = (const float*)d_in[8];
  const float* ig   = (const float*)d_in[9];
  const float* ib   = (const float*)d_in[10];
  const float* pw   = (const float*)d_in[11];
  const float* pb   = (const float*)d_in[12];
  const float* n1g  = (const float*)d_in[13];
  const float* n1b  = (const float*)d_in[14];
  const float* n2g  = (const float*)d_in[15];
  const float* n2b  = (const float*)d_in[16];
  const float* w1w  = (const float*)d_in[17];
  const float* w1b  = (const float*)d_in[18];
  const float* w2w  = (const float*)d_in[19];
  const float* w2b  = (const float*)d_in[20];
  const float* fg   = (const float*)d_in[21];
  const float* fb   = (const float*)d_in[22];
  const float* w3w  = (const float*)d_in[23];
  const float* w3b  = (const float*)d_in[24];

  const int M = 64 * 257;        // 16448
  const int D = 1024, HD = 4096;
  char* ws = (char*)d_ws;
  const size_t CHB = (size_t)M * D * 2;          // 33,685,504 B (bf16 channel buffer)
  // ws layout: 4 channel buffers (4*CHB = 134.7 MB) + bf16 weights (33.6 MB) = 168.3 MB
  bf16* B0 = (bf16*)(ws);
  bf16* B1 = (bf16*)(ws + CHB);
  bf16* B2 = (bf16*)(ws + 2*CHB);
  bf16* B3 = (bf16*)(ws + 3*CHB);
  bf16* WQ = (bf16*)(ws + 4*CHB);
  bf16* WK = WQ + (size_t)D*D;
  bf16* WV = WK + (size_t)D*D;
  bf16* WP = WV + (size_t)D*D;
  bf16* W1 = WP + (size_t)D*D;
  bf16* W2 = W1 + (size_t)HD*D;
  bf16* W3 = W2 + (size_t)HD*D;
  bf16* XN  = B0;          // LN1 out
  bf16* Qb  = B1;
  bf16* Kbf = B2;
  bf16* Vbf = B3;
  bf16* AO  = B0;          // XN dead after V GEMM
  bf16* AOL = B1;          // Q dead after attention
  bf16* X1  = B2;          // K dead after attention
  bf16* XN2 = B3;          // V dead after LN2
  bf16* HS  = B0;          // 2*CHB region (B0+B1): AO/AOL dead — per-FFN-chunk hidden
  float* OUT = (float*)d_out;

  dim3 blk(256);
  dim3 g1(D/128, (M + 127)/128);

  // weight conversion f32 -> bf16 (graph-captured; ~25 µs total, saves VALU+bytes in every GEMM)
  const int n8_D = D*D/8;      // 131072
  const int n8_H = HD*D/8;     // 524288
  cvt_kernel<<<dim3(n8_D/256), blk, 0, stream>>>(q_w, WQ, n8_D);
  cvt_kernel<<<dim3(n8_D/256), blk, 0, stream>>>(k_w, WK, n8_D);
  cvt_kernel<<<dim3(n8_D/256), blk, 0, stream>>>(v_w, WV, n8_D);
  cvt_kernel<<<dim3(n8_D/256), blk, 0, stream>>>(pw,  WP, n8_D);
  cvt_kernel<<<dim3(n8_H/256), blk, 0, stream>>>(w1w, W1, n8_H);
  cvt_kernel<<<dim3(n8_H/256), blk, 0, stream>>>(w2w, W2, n8_H);
  cvt_kernel<<<dim3(n8_H/256), blk, 0, stream>>>(w3w, W3, n8_H);

  ln_kernel<1024, float><<<dim3(M), blk, 0, stream>>>(x, n1g, n1b, XN, M);
  gemm_bt<bf16, bf16><<<g1, blk, 0, stream>>>(XN, WQ, q_b, (const bf16*)nullptr, Qb, M, D, D, 0);
  gemm_bt<bf16, bf16><<<g1, blk, 0, stream>>>(XN, WK, nullptr, (const bf16*)nullptr, Kbf, M, D, D, 0);
  gemm_bt<bf16, bf16><<<g1, blk, 0, stream>>>(XN, WV, v_b, (const bf16*)nullptr, Vbf, M, D, D, 0);
  rope_kernel<<<dim3(64*256*512/256), blk, 0, stream>>>(Qb, Kbf, rc, rsn);
  attn_kernel<<<dim3(64*16*17), blk, 0, stream>>>(Qb, Kbf, Vbf, tab, AO);
  ln_kernel<1024, bf16><<<dim3(M), blk, 0, stream>>>(AO, ig, ib, AOL, M);
  gemm_bt<float, bf16><<<g1, blk, 0, stream>>>(AOL, WP, pb, x, X1, M, D, D, 1);
  ln_kernel<1024, bf16><<<dim3(M), blk, 0, stream>>>(X1, n2g, n2b, XN2, M);

  // FFN in two M/2 row-chunks so hidden fits in 2*CHB
  const int MC = M / 2;                       // 8224
  dim3 g2(HD/128, (MC + 127)/128);
  dim3 g1c(D/128, (MC + 127)/128);
  for (int c = 0; c < 2; c++){
    const bf16* a2 = XN2 + (size_t)c * MC * D;
    const bf16* x1 = X1  + (size_t)c * MC * D;
    float*      oc = OUT + (size_t)c * MC * D;
    gemm_bt<bf16, bf16><<<g2, blk, 0, stream>>>(a2, W1, w1b, (const bf16*)nullptr, HS, MC, HD, D, 0);
    gemm_bt<bf16, bf16><<<g2, blk, 0, stream>>>(a2, W2, w2b, HS, HS, MC, HD, D, 2);
    ln_kernel<4096, bf16><<<dim3(MC), blk, 0, stream>>>(HS, fg, fb, HS, MC);
    gemm_bt<bf16, float><<<g1c, blk, 0, stream>>>(HS, W3, w3b, x1, oc, MC, D, HD, 1);
  }
}

// Round 3
// 1657.682 us; speedup vs baseline: 1.1256x; 1.1256x over previous
//
#include <hip/hip_runtime.h>
#include <stdint.h>

typedef __bf16 bf16;
typedef __attribute__((ext_vector_type(8))) __bf16 bf16x8;
typedef __attribute__((ext_vector_type(4))) float floatx4;

__device__ inline float bflo(uint32_t u){ union{uint32_t v; float f;} t; t.v = u << 16; return t.f; }
__device__ inline float bfhi(uint32_t u){ union{uint32_t v; float f;} t; t.v = u & 0xffff0000u; return t.f; }
__device__ inline uint32_t pack2(float a, float b){ union{ bf16 h[2]; uint32_t u; } t; t.h[0]=(bf16)a; t.h[1]=(bf16)b; return t.u; }

__device__ inline void load4(const bf16* p, float* x){
  uint2 u = *(const uint2*)p; x[0]=bflo(u.x); x[1]=bfhi(u.x); x[2]=bflo(u.y); x[3]=bfhi(u.y);
}
__device__ inline void load4(const float* p, float* x){
  float4 u = *(const float4*)p; x[0]=u.x; x[1]=u.y; x[2]=u.z; x[3]=u.w;
}

// async global->LDS, 16B per lane (dest must be wave-uniform base + lane*16)
__device__ inline void gload16(const void* g, void* l){
  __builtin_amdgcn_global_load_lds((const __attribute__((address_space(1))) uint32_t*)g,
                                   (__attribute__((address_space(3))) uint32_t*)l, 16, 0, 0);
}

// ---------------- f32 -> bf16 weight conversion (once per launch; scale folds Q's 1/8) ----------------
__global__ __launch_bounds__(256) void cvt_kernel(const float* __restrict__ in, bf16* __restrict__ out,
                                                  int n8, float scale)
{
  int i = blockIdx.x * 256 + threadIdx.x;
  if (i >= n8) return;
  const float* p = in + (size_t)i * 8;
  float4 a = *(const float4*)p;
  float4 b = *(const float4*)(p + 4);
  union{ uint4 q; bf16 h[8]; } pk;
  pk.h[0]=(bf16)(a.x*scale); pk.h[1]=(bf16)(a.y*scale); pk.h[2]=(bf16)(a.z*scale); pk.h[3]=(bf16)(a.w*scale);
  pk.h[4]=(bf16)(b.x*scale); pk.h[5]=(bf16)(b.y*scale); pk.h[6]=(bf16)(b.z*scale); pk.h[7]=(bf16)(b.w*scale);
  *(uint4*)(out + (size_t)i*8) = pk.q;
}

// ---------------- fused QKV bias vector: [q_b*0.125 | 0 | v_b] ----------------
__global__ __launch_bounds__(256) void qkvb_fill(const float* __restrict__ qb, const float* __restrict__ vb,
                                                 float* __restrict__ out)
{
  int i = blockIdx.x * 256 + threadIdx.x;   // 3072
  float v = 0.f;
  if (i < 1024) v = qb[i] * 0.125f;
  else if (i >= 2048) v = vb[i - 2048];
  out[i] = v;
}

// ---------------- rel-pos bias matrix precompute: biasB[h][272][272] bf16; kg>256 = -3e38 (mask) ----------------
__global__ __launch_bounds__(256) void bias_fill(const float* __restrict__ tab, bf16* __restrict__ biasB)
{
  int t = blockIdx.x * 256 + threadIdx.x;
  if (t >= 16*272*272) return;
  int kg = t % 272;
  int rem = t / 272;
  int qg = rem % 272;
  int h = rem / 272;
  float v;
  if (kg > 256) v = -3e38f;
  else {
    int qq = min(qg, 256);
    int idx;
    if (qq == 0 && kg == 0) idx = 963;
    else if (qq == 0) idx = 961;
    else if (kg == 0) idx = 962;
    else { int p = qq - 1, pk = kg - 1;
           idx = ((p >> 4) - (pk >> 4) + 15) * 31 + ((p & 15) - (pk & 15) + 15); }
    v = tab[idx*16 + h];
  }
  biasB[t] = (bf16)v;
}

// ---------------- LayerNorm (row-per-block, width W). In-place safe. ----------------
template<int W, typename TIN>
__global__ __launch_bounds__(256) void ln_kernel(const TIN* in, const float* __restrict__ g,
                                                 const float* __restrict__ bb, bf16* out, int M)
{
  constexpr int E = W / 256;
  int row = blockIdx.x; if (row >= M) return;
  int tid = threadIdx.x;
  const TIN* rp = in + (size_t)row * W + tid * E;
  float x[E];
  #pragma unroll
  for (int j = 0; j < E; j += 4) load4(rp + j, &x[j]);
  float s = 0.f, ss = 0.f;
  #pragma unroll
  for (int e = 0; e < E; e++){ s += x[e]; ss += x[e]*x[e]; }
  #pragma unroll
  for (int k = 32; k >= 1; k >>= 1){ s += __shfl_xor(s, k, 64); ss += __shfl_xor(ss, k, 64); }
  __shared__ float rs_[4], rq_[4];
  if ((tid & 63) == 0){ rs_[tid >> 6] = s; rq_[tid >> 6] = ss; }
  __syncthreads();
  s = rs_[0]+rs_[1]+rs_[2]+rs_[3]; ss = rq_[0]+rq_[1]+rq_[2]+rq_[3];
  float mean = s * (1.0f / W);
  float var  = ss * (1.0f / W) - mean * mean;
  float rinv = rsqrtf(var + 1e-5f);
  bf16* op = out + (size_t)row * W + tid * E;
  const float* gp = g + tid * E;
  const float* bp = bb + tid * E;
  #pragma unroll
  for (int j = 0; j < E; j += 4){
    float gv[4], bv[4];
    load4(gp + j, gv); load4(bp + j, bv);
    float y0 = (x[j]  -mean)*rinv*gv[0] + bv[0];
    float y1 = (x[j+1]-mean)*rinv*gv[1] + bv[1];
    float y2 = (x[j+2]-mean)*rinv*gv[2] + bv[2];
    float y3 = (x[j+3]-mean)*rinv*gv[3] + bv[3];
    uint2 o; o.x = pack2(y0, y1); o.y = pack2(y2, y3);
    *(uint2*)(op + j) = o;
  }
}

// ---------------- NT GEMM (unchanged from passing round): global_load_lds staging, 128x128 tile ----------------
template<typename TE, typename TC>
__global__ __launch_bounds__(256) void gemm_bt(const bf16* __restrict__ A, const bf16* __restrict__ Bw,
                                               const float* __restrict__ bias, const TE* extra,
                                               TC* C, int M, int N, int K, int mode)
{
  __shared__ __align__(16) bf16 As[128*32];
  __shared__ __align__(16) bf16 Bs[128*32];
  int tid = threadIdx.x;
  int lane = tid & 63, wave = tid >> 6;
  int l16 = lane & 15, quad = lane >> 4;
  int wm = wave >> 1, wn = wave & 1;
  int m0 = blockIdx.y * 128, n0 = blockIdx.x * 128;
  floatx4 acc[4][4];
  #pragma unroll
  for (int i = 0; i < 4; i++)
    #pragma unroll
    for (int j = 0; j < 4; j++) acc[i][j] = (floatx4){0.f,0.f,0.f,0.f};
  int nk = K >> 5;
  int rowS = tid >> 2;
  int colS = (tid & 3) * 8;
  int ra0 = min(m0 + rowS,      M-1);
  int ra1 = min(m0 + 64 + rowS, M-1);
  int rb0 = min(n0 + rowS,      N-1);
  int rb1 = min(n0 + 64 + rowS, N-1);
  const bf16* pa0 = A  + (size_t)ra0 * K + colS;
  const bf16* pa1 = A  + (size_t)ra1 * K + colS;
  const bf16* pb0 = Bw + (size_t)rb0 * K + colS;
  const bf16* pb1 = Bw + (size_t)rb1 * K + colS;
  bf16* la0 = &As[tid*8];        bf16* la1 = &As[2048 + tid*8];
  bf16* lb0 = &Bs[tid*8];        bf16* lb1 = &Bs[2048 + tid*8];
  auto stage = [&](int kt){
    int ko = kt * 32;
    gload16(pa0 + ko, la0);
    gload16(pa1 + ko, la1);
    gload16(pb0 + ko, lb0);
    gload16(pb1 + ko, lb1);
  };
  stage(0);
  int kt = 0;
  while (true){
    __syncthreads();
    bf16x8 af[4], bfv[4];
    #pragma unroll
    for (int i = 0; i < 4; i++) af[i]  = *(const bf16x8*)&As[(wm*64 + i*16 + l16)*32 + quad*8];
    #pragma unroll
    for (int j = 0; j < 4; j++) bfv[j] = *(const bf16x8*)&Bs[(wn*64 + j*16 + l16)*32 + quad*8];
    ++kt;
    bool more = kt < nk;
    if (more){
      __syncthreads();
      stage(kt);
    }
    #pragma unroll
    for (int i = 0; i < 4; i++)
      #pragma unroll
      for (int j = 0; j < 4; j++)
        acc[i][j] = __builtin_amdgcn_mfma_f32_16x16x32_bf16(af[i], bfv[j], acc[i][j], 0, 0, 0);
    if (!more) break;
  }
  #pragma unroll
  for (int i = 0; i < 4; i++){
    int gmb = m0 + wm*64 + i*16 + quad*4;
    #pragma unroll
    for (int j = 0; j < 4; j++){
      int gn = n0 + wn*64 + j*16 + l16;
      float bv = bias ? bias[gn] : 0.f;
      #pragma unroll
      for (int r = 0; r < 4; r++){
        int gm = gmb + r;
        if (gm < M){
          float v = acc[i][j][r] + bv;
          if (mode == 1) v += (float)extra[(size_t)gm * N + gn];
          else if (mode == 2){ float a = (float)extra[(size_t)gm * N + gn]; v *= a / (1.f + __expf(-a)); }
          C[(size_t)gm * N + gn] = (TC)v;
        }
      }
    }
  }
}

// ---------------- RoPE on fused QKV buffer [M][3072]: q at +0, k at +1024; tokens 1..256 ----------------
__global__ __launch_bounds__(256) void rope_kernel(bf16* __restrict__ qkv,
                                                   const float* __restrict__ cs, const float* __restrict__ sn)
{
  uint32_t i = blockIdx.x * 256u + threadIdx.x;   // 64*256*512 pairs
  int d0 = (int)(i & 511) * 2;
  int tok = (int)((i >> 9) & 255);
  int b = (int)(i >> 17);
  int j = d0 & 63;
  float c0 = cs[tok*64 + j], c1 = cs[tok*64 + j + 1];
  float s0 = sn[tok*64 + j], s1 = sn[tok*64 + j + 1];
  size_t off = ((size_t)(b*257 + tok + 1)) * 3072 + d0;
  uint32_t uq = *(const uint32_t*)(qkv + off);
  float x0 = bflo(uq), x1 = bfhi(uq);
  *(uint32_t*)(qkv + off) = pack2(x0*c0 - x1*s0, x1*c1 + x0*s1);
  uint32_t uk = *(const uint32_t*)(qkv + off + 1024);
  float y0 = bflo(uk), y1 = bfhi(uk);
  *(uint32_t*)(qkv + off + 1024) = pack2(y0*c0 - y1*s0, y1*c1 + y0*s1);
}

// ---------------- attention v2: one block per (b,h); 4 independent waves; full-row softmax in regs ----------------
// Swapped QK^T: mfma(a=K-rows, b=Q-rows) -> lane(l16,quad) holds S[q=l16][k=nt*16+quad*4+r].
// K staged via global_load_lds with XOR-swizzled SOURCE (seg ^= row&7) -> conflict-free ds_read_b128.
// V staged transposed Vt[64][296] (pair-packed u32 writes, conflict-free; cols >256 zeroed).
// P redistributed to A-frag layout via 8 quad-shuffles per 32-k chunk; PV accumulates in regs.
__global__ __launch_bounds__(256, 2) void attn_kernel(const bf16* __restrict__ QKV,
                                                      const bf16* __restrict__ biasB,
                                                      bf16* __restrict__ AO)
{
  __shared__ __align__(16) bf16 Ks[272*64];      // 34816 B (rows 257..271 = dup of row 256, masked via bias)
  __shared__ __align__(16) bf16 Vt[64*296];      // 37888 B (V^T, col pad 272..287 zeroed)
  int id = blockIdx.x;
  int h = id & 15, b = id >> 4;
  int tid = threadIdx.x, lane = tid & 63, wave = tid >> 6;
  int l16 = lane & 15, quad = lane >> 4;
  size_t baseQ = (size_t)(b*257) * 3072 + h*64;
  const bf16* Kg = QKV + baseQ + 1024;
  const bf16* Vg = QKV + baseQ + 2048;
  size_t aoBase = (size_t)(b*257) * 1024 + h*64;

  // --- stage K: LDS[row][seg] = Kglobal[min(row,256)][seg ^ (row&7)]  (linear dest, swizzled source) ---
  for (int i = tid; i < 272*8; i += 256){
    int row = i >> 3, seg = i & 7;
    int tok = min(row, 256);
    gload16(Kg + (size_t)tok*3072 + ((seg ^ (row & 7)) * 8), &Ks[i*8]);
  }
  // --- stage V^T: Vt[d][trow], token pairs packed as u32 writes ---
  for (int i = tid; i < 144*8; i += 256){
    int tp = (i % 144) * 2, dseg = i / 144;
    uint4 u0 = make_uint4(0,0,0,0), u1 = make_uint4(0,0,0,0);
    if (tp     <= 256) u0 = *(const uint4*)(Vg + (size_t)tp*3072 + dseg*8);
    if (tp + 1 <= 256) u1 = *(const uint4*)(Vg + (size_t)(tp+1)*3072 + dseg*8);
    union { uint4 q4; bf16 h8[8]; } va, vb2; va.q4 = u0; vb2.q4 = u1;
    #pragma unroll
    for (int jj = 0; jj < 8; jj++){
      union { uint32_t u; bf16 hh[2]; } w; w.hh[0] = va.h8[jj]; w.hh[1] = vb2.h8[jj];
      *(uint32_t*)&Vt[(dseg*8 + jj)*296 + tp] = w.u;
    }
  }
  __syncthreads();

  int srcA = l16 + 16*((2*quad)     & 3);   // shuffle source lanes (frag words w=0,1)
  int srcB = l16 + 16*((2*quad + 1) & 3);   // (frag words w=2,3)

  for (int qt = wave; qt < 17; qt += 4){
    int q0 = qt * 16;
    int qrow = min(q0 + l16, 256);
    const bf16* qp = QKV + baseQ + (size_t)qrow*3072;
    bf16x8 qb0 = *(const bf16x8*)(qp + quad*8);          // Q pre-scaled by 0.125 (folded into WQ)
    bf16x8 qb1 = *(const bf16x8*)(qp + 32 + quad*8);

    // S^T tiles: lane holds S[q=l16][k = nt*16 + quad*4 + r]
    floatx4 S[17];
    #pragma unroll
    for (int nt = 0; nt < 17; nt++){
      int row = nt*16 + l16;
      bf16x8 ka0 = *(const bf16x8*)&Ks[row*64 + ((quad     ^ (l16 & 7)) * 8)];
      bf16x8 ka1 = *(const bf16x8*)&Ks[row*64 + (((4+quad) ^ (l16 & 7)) * 8)];
      floatx4 c = (floatx4){0.f,0.f,0.f,0.f};
      c = __builtin_amdgcn_mfma_f32_16x16x32_bf16(ka0, qb0, c, 0, 0, 0);
      c = __builtin_amdgcn_mfma_f32_16x16x32_bf16(ka1, qb1, c, 0, 0, 0);
      S[nt] = c;
    }

    // bias add (mask folded into bias: kg>256 -> -3e38) + row max
    const bf16* bp = biasB + ((size_t)(h*272) + (q0 + l16)) * 272;
    float m = -3e38f;
    #pragma unroll
    for (int nt = 0; nt < 17; nt++){
      uint2 bu = *(const uint2*)(bp + nt*16 + quad*4);
      S[nt][0] += bflo(bu.x); S[nt][1] += bfhi(bu.x);
      S[nt][2] += bflo(bu.y); S[nt][3] += bfhi(bu.y);
      m = fmaxf(m, fmaxf(fmaxf(S[nt][0], S[nt][1]), fmaxf(S[nt][2], S[nt][3])));
    }
    m = fmaxf(m, __shfl_xor(m, 16, 64));
    m = fmaxf(m, __shfl_xor(m, 32, 64));

    // exp + pack to bf16 pairs + row sum
    float lsum = 0.f;
    uint32_t pklo[17], pkhi[17];
    #pragma unroll
    for (int nt = 0; nt < 17; nt++){
      float p0 = __expf(S[nt][0] - m), p1 = __expf(S[nt][1] - m);
      float p2 = __expf(S[nt][2] - m), p3 = __expf(S[nt][3] - m);
      lsum += (p0 + p1) + (p2 + p3);
      pklo[nt] = pack2(p0, p1); pkhi[nt] = pack2(p2, p3);
    }
    lsum += __shfl_xor(lsum, 16, 64);
    lsum += __shfl_xor(lsum, 32, 64);

    // PV: build P a-frags via quad shuffles, accumulate O[q][d]
    floatx4 o[4];
    #pragma unroll
    for (int dt = 0; dt < 4; dt++) o[dt] = (floatx4){0.f,0.f,0.f,0.f};
    #pragma unroll
    for (int ks = 0; ks < 9; ks++){
      uint32_t t0[4], t1[4];
      t0[0] = (uint32_t)__shfl((int)pklo[2*ks], srcA, 64);
      t0[1] = (uint32_t)__shfl((int)pkhi[2*ks], srcA, 64);
      t0[2] = (uint32_t)__shfl((int)pklo[2*ks], srcB, 64);
      t0[3] = (uint32_t)__shfl((int)pkhi[2*ks], srcB, 64);
      if (2*ks + 1 <= 16){
        t1[0] = (uint32_t)__shfl((int)pklo[2*ks+1], srcA, 64);
        t1[1] = (uint32_t)__shfl((int)pkhi[2*ks+1], srcA, 64);
        t1[2] = (uint32_t)__shfl((int)pklo[2*ks+1], srcB, 64);
        t1[3] = (uint32_t)__shfl((int)pkhi[2*ks+1], srcB, 64);
      } else {
        t1[0] = 0; t1[1] = 0; t1[2] = 0; t1[3] = 0;
      }
      union { uint32_t u[4]; bf16x8 v; } pa;
      bool lowhalf = (quad < 2);
      pa.u[0] = lowhalf ? t0[0] : t1[0];
      pa.u[1] = lowhalf ? t0[1] : t1[1];
      pa.u[2] = lowhalf ? t0[2] : t1[2];
      pa.u[3] = lowhalf ? t0[3] : t1[3];
      #pragma unroll
      for (int dt = 0; dt < 4; dt++){
        bf16x8 vb = *(const bf16x8*)&Vt[(dt*16 + l16)*296 + ks*32 + quad*8];
        o[dt] = __builtin_amdgcn_mfma_f32_16x16x32_bf16(pa.v, vb, o[dt], 0, 0, 0);
      }
    }

    // epilogue: normalize + store (output q = q0 + quad*4 + r, d = dt*16 + l16)
    #pragma unroll
    for (int r = 0; r < 4; r++){
      int q = q0 + quad*4 + r;
      float ls = __shfl(lsum, quad*4 + r, 64);
      float rinv = 1.0f / ls;
      if (q <= 256){
        #pragma unroll
        for (int dt = 0; dt < 4; dt++)
          AO[aoBase + (size_t)q*1024 + dt*16 + l16] = (bf16)(o[dt][r] * rinv);
      }
    }
  }
}

extern "C" void kernel_launch(void* const* d_in, const int* in_sizes, int n_in,
                              void* d_out, int out_size, void* d_ws, size_t ws_size,
                              hipStream_t stream)
{
  (void)in_sizes; (void)n_in; (void)out_size; (void)ws_size;
  const float* x    = (const float*)d_in[0];
  const float* rc   = (const float*)d_in[1];
  const float* rsn  = (const float*)d_in[2];
  const float* q_w  = (const float*)d_in[3];
  const float* q_b  = (const float*)d_in[4];
  const float* k_w  = (const float*)d_in[5];
  const float* v_w  = (const float*)d_in[6];
  const float* v_b  = (const float*)d_in[7];
  const float* tab  = (const float*)d_in[8];
  const float* ig   = (const float*)d_in[9];
  const float* ib   = (const float*)d_in[10];
  const float* pw   = (const float*)d_in[11];
  const float* pb   = (const float*)d_in[12];
  const float* n1g  = (const float*)d_in[13];
  const float* n1b  = (const float*)d_in[14];
  const float* n2g  = (const float*)d_in[15];
  const float* n2b  = (const float*)d_in[16];
  const float* w1w  = (const float*)d_in[17];
  const float* w1b  = (const float*)d_in[18];
  const float* w2w  = (const float*)d_in[19];
  const float* w2b  = (const float*)d_in[20];
  const float* fg   = (const float*)d_in[21];
  const float* fb   = (const float*)d_in[22];
  const float* w3w  = (const float*)d_in[23];
  const float* w3b  = (const float*)d_in[24];

  const int M = 64 * 257;        // 16448
  const int D = 1024, HD = 4096;
  char* ws = (char*)d_ws;
  const size_t CHB = (size_t)M * D * 2;          // 33,685,504 B
  // ws layout: 4 channel buffers + bf16 weights (32 MB) + qkv bias (12 KB)
  bf16* B0 = (bf16*)(ws);
  bf16* B1 = (bf16*)(ws + CHB);
  bf16* B2 = (bf16*)(ws + 2*CHB);
  bf16* B3 = (bf16*)(ws + 3*CHB);
  bf16* WQ = (bf16*)(ws + 4*CHB);
  bf16* WK = WQ + (size_t)D*D;
  bf16* WV = WK + (size_t)D*D;
  bf16* WP = WV + (size_t)D*D;
  bf16* W1 = WP + (size_t)D*D;
  bf16* W2 = W1 + (size_t)HD*D;
  bf16* W3 = W2 + (size_t)HD*D;
  float* QKVB = (float*)(W3 + (size_t)HD*D);
  bf16* XN  = B0;          // LN1 out
  bf16* QKV = B1;          // fused [M][3072] spans B1..B3
  bf16* AO  = B0;          // XN dead after QKV GEMM
  bf16* AOL = B1;          // QKV dead after attention
  bf16* X1  = B2;
  bf16* XN2 = B3;
  bf16* HS  = B0;          // spans B0+B1 during FFN
  bf16* biasB = (bf16*)d_out;   // 2.37 MB scratch in d_out; dead before FFN writes OUT
  float* OUT = (float*)d_out;

  dim3 blk(256);
  dim3 g1(D/128, (M + 127)/128);
  dim3 gqkv(3072/128, (M + 127)/128);

  const int n8_D = D*D/8;      // 131072
  const int n8_H = HD*D/8;     // 524288
  cvt_kernel<<<dim3(n8_D/256), blk, 0, stream>>>(q_w, WQ, n8_D, 0.125f);  // fold attn scale into Q
  cvt_kernel<<<dim3(n8_D/256), blk, 0, stream>>>(k_w, WK, n8_D, 1.f);
  cvt_kernel<<<dim3(n8_D/256), blk, 0, stream>>>(v_w, WV, n8_D, 1.f);
  cvt_kernel<<<dim3(n8_D/256), blk, 0, stream>>>(pw,  WP, n8_D, 1.f);
  cvt_kernel<<<dim3(n8_H/256), blk, 0, stream>>>(w1w, W1, n8_H, 1.f);
  cvt_kernel<<<dim3(n8_H/256), blk, 0, stream>>>(w2w, W2, n8_H, 1.f);
  cvt_kernel<<<dim3(n8_H/256), blk, 0, stream>>>(w3w, W3, n8_H, 1.f);
  qkvb_fill<<<dim3(12), blk, 0, stream>>>(q_b, v_b, QKVB);
  bias_fill<<<dim3((16*272*272 + 255)/256), blk, 0, stream>>>(tab, biasB);

  ln_kernel<1024, float><<<dim3(M), blk, 0, stream>>>(x, n1g, n1b, XN, M);
  gemm_bt<bf16, bf16><<<gqkv, blk, 0, stream>>>(XN, WQ, QKVB, (const bf16*)nullptr, QKV, M, 3072, D, 0);
  rope_kernel<<<dim3(64*256*512/256), blk, 0, stream>>>(QKV, rc, rsn);
  attn_kernel<<<dim3(64*16), blk, 0, stream>>>(QKV, biasB, AO);
  ln_kernel<1024, bf16><<<dim3(M), blk, 0, stream>>>(AO, ig, ib, AOL, M);
  gemm_bt<float, bf16><<<g1, blk, 0, stream>>>(AOL, WP, pb, x, X1, M, D, D, 1);
  ln_kernel<1024, bf16><<<dim3(M), blk, 0, stream>>>(X1, n2g, n2b, XN2, M);

  const int MC = M / 2;                       // 8224
  dim3 g2(HD/128, (MC + 127)/128);
  dim3 g1c(D/128, (MC + 127)/128);
  for (int c = 0; c < 2; c++){
    const bf16* a2 = XN2 + (size_t)c * MC * D;
    const bf16* x1 = X1  + (size_t)c * MC * D;
    float*      oc = OUT + (size_t)c * MC * D;
    gemm_bt<bf16, bf16><<<g2, blk, 0, stream>>>(a2, W1, w1b, (const bf16*)nullptr, HS, MC, HD, D, 0);
    gemm_bt<bf16, bf16><<<g2, blk, 0, stream>>>(a2, W2, w2b, HS, HS, MC, HD, D, 2);
    ln_kernel<4096, bf16><<<dim3(MC), blk, 0, stream>>>(HS, fg, fb, HS, MC);
    gemm_bt<bf16, float><<<g1c, blk, 0, stream>>>(HS, W3, w3b, x1, oc, MC, D, HD, 1);
  }
}

// Round 5
// 1617.035 us; speedup vs baseline: 1.1538x; 1.0251x over previous
//
#include <hip/hip_runtime.h>
#include <stdint.h>

typedef __bf16 bf16;
typedef __attribute__((ext_vector_type(8))) __bf16 bf16x8;
typedef __attribute__((ext_vector_type(4))) float floatx4;

__device__ inline float bflo(uint32_t u){ union{uint32_t v; float f;} t; t.v = u << 16; return t.f; }
__device__ inline float bfhi(uint32_t u){ union{uint32_t v; float f;} t; t.v = u & 0xffff0000u; return t.f; }
__device__ inline uint32_t pack2(float a, float b){ union{ bf16 h[2]; uint32_t u; } t; t.h[0]=(bf16)a; t.h[1]=(bf16)b; return t.u; }

__device__ inline void load4(const bf16* p, float* x){
  uint2 u = *(const uint2*)p; x[0]=bflo(u.x); x[1]=bfhi(u.x); x[2]=bflo(u.y); x[3]=bfhi(u.y);
}
__device__ inline void load4(const float* p, float* x){
  float4 u = *(const float4*)p; x[0]=u.x; x[1]=u.y; x[2]=u.z; x[3]=u.w;
}

// async global->LDS, 16B per lane (dest must be wave-uniform base + lane*16)
__device__ inline void gload16(const void* g, void* l){
  __builtin_amdgcn_global_load_lds((const __attribute__((address_space(1))) uint32_t*)g,
                                   (__attribute__((address_space(3))) uint32_t*)l, 16, 0, 0);
}

// ---------------- f32 -> bf16 weight conversion (once per launch; scale folds Q's 1/8) ----------------
__global__ __launch_bounds__(256) void cvt_kernel(const float* __restrict__ in, bf16* __restrict__ out,
                                                  int n8, float scale)
{
  int i = blockIdx.x * 256 + threadIdx.x;
  if (i >= n8) return;
  const float* p = in + (size_t)i * 8;
  float4 a = *(const float4*)p;
  float4 b = *(const float4*)(p + 4);
  union{ uint4 q; bf16 h[8]; } pk;
  pk.h[0]=(bf16)(a.x*scale); pk.h[1]=(bf16)(a.y*scale); pk.h[2]=(bf16)(a.z*scale); pk.h[3]=(bf16)(a.w*scale);
  pk.h[4]=(bf16)(b.x*scale); pk.h[5]=(bf16)(b.y*scale); pk.h[6]=(bf16)(b.z*scale); pk.h[7]=(bf16)(b.w*scale);
  *(uint4*)(out + (size_t)i*8) = pk.q;
}

// ---------------- fused QKV bias vector: [q_b*0.125 | 0 | v_b] ----------------
__global__ __launch_bounds__(256) void qkvb_fill(const float* __restrict__ qb, const float* __restrict__ vb,
                                                 float* __restrict__ out)
{
  int i = blockIdx.x * 256 + threadIdx.x;   // 3072
  float v = 0.f;
  if (i < 1024) v = qb[i] * 0.125f;
  else if (i >= 2048) v = vb[i - 2048];
  out[i] = v;
}

// ---------------- rel-pos bias matrix precompute: biasB[h][272][272] bf16; kg>256 = -3e38 (mask) ----------------
__global__ __launch_bounds__(256) void bias_fill(const float* __restrict__ tab, bf16* __restrict__ biasB)
{
  int t = blockIdx.x * 256 + threadIdx.x;
  if (t >= 16*272*272) return;
  int kg = t % 272;
  int rem = t / 272;
  int qg = rem % 272;
  int h = rem / 272;
  float v;
  if (kg > 256) v = -3e38f;
  else {
    int qq = min(qg, 256);
    int idx;
    if (qq == 0 && kg == 0) idx = 963;
    else if (qq == 0) idx = 961;
    else if (kg == 0) idx = 962;
    else { int p = qq - 1, pk = kg - 1;
           idx = ((p >> 4) - (pk >> 4) + 15) * 31 + ((p & 15) - (pk & 15) + 15); }
    v = tab[idx*16 + h];
  }
  biasB[t] = (bf16)v;
}

// ---------------- LayerNorm (row-per-block, width W). In-place safe. ----------------
template<int W, typename TIN>
__global__ __launch_bounds__(256) void ln_kernel(const TIN* in, const float* __restrict__ g,
                                                 const float* __restrict__ bb, bf16* out, int M)
{
  constexpr int E = W / 256;
  int row = blockIdx.x; if (row >= M) return;
  int tid = threadIdx.x;
  const TIN* rp = in + (size_t)row * W + tid * E;
  float x[E];
  #pragma unroll
  for (int j = 0; j < E; j += 4) load4(rp + j, &x[j]);
  float s = 0.f, ss = 0.f;
  #pragma unroll
  for (int e = 0; e < E; e++){ s += x[e]; ss += x[e]*x[e]; }
  #pragma unroll
  for (int k = 32; k >= 1; k >>= 1){ s += __shfl_xor(s, k, 64); ss += __shfl_xor(ss, k, 64); }
  __shared__ float rs_[4], rq_[4];
  if ((tid & 63) == 0){ rs_[tid >> 6] = s; rq_[tid >> 6] = ss; }
  __syncthreads();
  s = rs_[0]+rs_[1]+rs_[2]+rs_[3]; ss = rq_[0]+rq_[1]+rq_[2]+rq_[3];
  float mean = s * (1.0f / W);
  float var  = ss * (1.0f / W) - mean * mean;
  float rinv = rsqrtf(var + 1e-5f);
  bf16* op = out + (size_t)row * W + tid * E;
  const float* gp = g + tid * E;
  const float* bp = bb + tid * E;
  #pragma unroll
  for (int j = 0; j < E; j += 4){
    float gv[4], bv[4];
    load4(gp + j, gv); load4(bp + j, bv);
    float y0 = (x[j]  -mean)*rinv*gv[0] + bv[0];
    float y1 = (x[j+1]-mean)*rinv*gv[1] + bv[1];
    float y2 = (x[j+2]-mean)*rinv*gv[2] + bv[2];
    float y3 = (x[j+3]-mean)*rinv*gv[3] + bv[3];
    uint2 o; o.x = pack2(y0, y1); o.y = pack2(y2, y3);
    *(uint2*)(op + j) = o;
  }
}

// ---------------- NT GEMM (unchanged): global_load_lds staging, 128x128 tile ----------------
template<typename TE, typename TC>
__global__ __launch_bounds__(256) void gemm_bt(const bf16* __restrict__ A, const bf16* __restrict__ Bw,
                                               const float* __restrict__ bias, const TE* extra,
                                               TC* C, int M, int N, int K, int mode)
{
  __shared__ __align__(16) bf16 As[128*32];
  __shared__ __align__(16) bf16 Bs[128*32];
  int tid = threadIdx.x;
  int lane = tid & 63, wave = tid >> 6;
  int l16 = lane & 15, quad = lane >> 4;
  int wm = wave >> 1, wn = wave & 1;
  int m0 = blockIdx.y * 128, n0 = blockIdx.x * 128;
  floatx4 acc[4][4];
  #pragma unroll
  for (int i = 0; i < 4; i++)
    #pragma unroll
    for (int j = 0; j < 4; j++) acc[i][j] = (floatx4){0.f,0.f,0.f,0.f};
  int nk = K >> 5;
  int rowS = tid >> 2;
  int colS = (tid & 3) * 8;
  int ra0 = min(m0 + rowS,      M-1);
  int ra1 = min(m0 + 64 + rowS, M-1);
  int rb0 = min(n0 + rowS,      N-1);
  int rb1 = min(n0 + 64 + rowS, N-1);
  const bf16* pa0 = A  + (size_t)ra0 * K + colS;
  const bf16* pa1 = A  + (size_t)ra1 * K + colS;
  const bf16* pb0 = Bw + (size_t)rb0 * K + colS;
  const bf16* pb1 = Bw + (size_t)rb1 * K + colS;
  bf16* la0 = &As[tid*8];        bf16* la1 = &As[2048 + tid*8];
  bf16* lb0 = &Bs[tid*8];        bf16* lb1 = &Bs[2048 + tid*8];
  auto stage = [&](int kt){
    int ko = kt * 32;
    gload16(pa0 + ko, la0);
    gload16(pa1 + ko, la1);
    gload16(pb0 + ko, lb0);
    gload16(pb1 + ko, lb1);
  };
  stage(0);
  int kt = 0;
  while (true){
    __syncthreads();
    bf16x8 af[4], bfv[4];
    #pragma unroll
    for (int i = 0; i < 4; i++) af[i]  = *(const bf16x8*)&As[(wm*64 + i*16 + l16)*32 + quad*8];
    #pragma unroll
    for (int j = 0; j < 4; j++) bfv[j] = *(const bf16x8*)&Bs[(wn*64 + j*16 + l16)*32 + quad*8];
    ++kt;
    bool more = kt < nk;
    if (more){
      __syncthreads();
      stage(kt);
    }
    #pragma unroll
    for (int i = 0; i < 4; i++)
      #pragma unroll
      for (int j = 0; j < 4; j++)
        acc[i][j] = __builtin_amdgcn_mfma_f32_16x16x32_bf16(af[i], bfv[j], acc[i][j], 0, 0, 0);
    if (!more) break;
  }
  #pragma unroll
  for (int i = 0; i < 4; i++){
    int gmb = m0 + wm*64 + i*16 + quad*4;
    #pragma unroll
    for (int j = 0; j < 4; j++){
      int gn = n0 + wn*64 + j*16 + l16;
      float bv = bias ? bias[gn] : 0.f;
      #pragma unroll
      for (int r = 0; r < 4; r++){
        int gm = gmb + r;
        if (gm < M){
          float v = acc[i][j][r] + bv;
          if (mode == 1) v += (float)extra[(size_t)gm * N + gn];
          else if (mode == 2){ float a = (float)extra[(size_t)gm * N + gn]; v *= a / (1.f + __expf(-a)); }
          C[(size_t)gm * N + gn] = (TC)v;
        }
      }
    }
  }
}

// ---------------- RoPE on fused QKV buffer [M][3072]: q at +0, k at +1024; tokens 1..256 ----------------
__global__ __launch_bounds__(256) void rope_kernel(bf16* __restrict__ qkv,
                                                   const float* __restrict__ cs, const float* __restrict__ sn)
{
  uint32_t i = blockIdx.x * 256u + threadIdx.x;   // 64*256*512 pairs
  int d0 = (int)(i & 511) * 2;
  int tok = (int)((i >> 9) & 255);
  int b = (int)(i >> 17);
  int j = d0 & 63;
  float c0 = cs[tok*64 + j], c1 = cs[tok*64 + j + 1];
  float s0 = sn[tok*64 + j], s1 = sn[tok*64 + j + 1];
  size_t off = ((size_t)(b*257 + tok + 1)) * 3072 + d0;
  uint32_t uq = *(const uint32_t*)(qkv + off);
  float x0 = bflo(uq), x1 = bfhi(uq);
  *(uint32_t*)(qkv + off) = pack2(x0*c0 - x1*s0, x1*c1 + x0*s1);
  uint32_t uk = *(const uint32_t*)(qkv + off + 1024);
  float y0 = bflo(uk), y1 = bfhi(uk);
  *(uint32_t*)(qkv + off + 1024) = pack2(y0*c0 - y1*s0, y1*c1 + y0*s1);
}

// ---------------- attention v3: one block per (b,h); coalesced V stage + LDS-staged coalesced AO writes ----------------
// Swapped QK^T: mfma(a=K-rows, b=Q-rows) -> lane(l16,quad) holds S[q=l16][k=nt*16+quad*4+r].
// K staged via global_load_lds with XOR-swizzled SOURCE -> conflict-free ds_read_b128.
// V staged with COALESCED 128B row reads, transposed in-wave (shfl_xor(8) row-pairing) into Vt (u32 writes).
// AO epilogue: normalize -> per-wave LDS tile -> uint4 coalesced stores (128B/row).
__global__ __launch_bounds__(256, 2) void attn_kernel(const bf16* __restrict__ QKV,
                                                      const bf16* __restrict__ biasB,
                                                      bf16* __restrict__ AO)
{
  constexpr int VS = 280;                         // Vt row stride (2-way-free on PV reads, 16B aligned)
  __shared__ __align__(16) bf16 Ks[272*64];       // 34816 B
  __shared__ __align__(16) bf16 Vt[64*VS];        // 35840 B
  __shared__ __align__(16) bf16 Os[4][16*72];     //  9216 B  (per-wave O staging; total 79872 B -> 2 blk/CU)
  int id = blockIdx.x;
  int h = id & 15, b = id >> 4;
  int tid = threadIdx.x, lane = tid & 63, wave = tid >> 6;
  int l16 = lane & 15, quad = lane >> 4;
  size_t baseQ = (size_t)(b*257) * 3072 + h*64;
  const bf16* Kg = QKV + baseQ + 1024;
  const bf16* Vg = QKV + baseQ + 2048;
  size_t aoBase = (size_t)(b*257) * 1024 + h*64;

  // --- stage K: LDS[row][seg] = Kglobal[min(row,256)][seg ^ (row&7)] (linear dest, swizzled source) ---
  for (int i = tid; i < 272*8; i += 256){
    int row = i >> 3, seg = i & 7;
    int tok = min(row, 256);
    gload16(Kg + (size_t)tok*3072 + ((seg ^ (row & 7)) * 8), &Ks[i*8]);
  }
  // --- stage V^T: coalesced row reads (8 lanes x 16B per 128B row), in-wave pair transpose ---
  for (int i = tid; i < 272*8; i += 256){
    int row = i >> 3, seg = i & 7;               // consecutive lanes = consecutive segs of same row
    int tok = min(row, 256);                      // rows 257..271 dup row 256; masked via bias
    uint4 v = *(const uint4*)(Vg + (size_t)tok*3072 + seg*8);
    uint4 w;
    w.x = (uint32_t)__shfl_xor((int)v.x, 8, 64);  // partner = row^1, same seg
    w.y = (uint32_t)__shfl_xor((int)v.y, 8, 64);
    w.z = (uint32_t)__shfl_xor((int)v.z, 8, 64);
    w.w = (uint32_t)__shfl_xor((int)v.w, 8, 64);
    union { uint4 q4; bf16 h8[8]; } mv, pv; mv.q4 = v; pv.q4 = w;
    int rb = row & ~1;
    if ((row & 1) == 0){
      #pragma unroll
      for (int jj = 0; jj < 4; jj++){
        union { uint32_t u; bf16 hh[2]; } pk; pk.hh[0] = mv.h8[jj]; pk.hh[1] = pv.h8[jj];
        *(uint32_t*)&Vt[(seg*8 + jj)*VS + rb] = pk.u;
      }
    } else {
      #pragma unroll
      for (int jj = 4; jj < 8; jj++){
        union { uint32_t u; bf16 hh[2]; } pk; pk.hh[0] = pv.h8[jj]; pk.hh[1] = mv.h8[jj];
        *(uint32_t*)&Vt[(seg*8 + jj)*VS + rb] = pk.u;
      }
    }
  }
  __syncthreads();

  int srcA = l16 + 16*((2*quad)     & 3);
  int srcB = l16 + 16*((2*quad + 1) & 3);

  for (int qt = wave; qt < 17; qt += 4){
    int q0 = qt * 16;
    int qrow = min(q0 + l16, 256);
    const bf16* qp = QKV + baseQ + (size_t)qrow*3072;
    bf16x8 qb0 = *(const bf16x8*)(qp + quad*8);          // Q pre-scaled by 0.125 (folded into WQ)
    bf16x8 qb1 = *(const bf16x8*)(qp + 32 + quad*8);

    // prefetch bias tile into regs (flies under the MFMA chain)
    const bf16* bp = biasB + ((size_t)(h*272) + (q0 + l16)) * 272;
    uint2 bu[17];
    #pragma unroll
    for (int nt = 0; nt < 17; nt++) bu[nt] = *(const uint2*)(bp + nt*16 + quad*4);

    // S^T tiles: lane holds S[q=l16][k = nt*16 + quad*4 + r]
    floatx4 S[17];
    #pragma unroll
    for (int nt = 0; nt < 17; nt++){
      int row = nt*16 + l16;
      bf16x8 ka0 = *(const bf16x8*)&Ks[row*64 + ((quad     ^ (l16 & 7)) * 8)];
      bf16x8 ka1 = *(const bf16x8*)&Ks[row*64 + (((4+quad) ^ (l16 & 7)) * 8)];
      floatx4 c = (floatx4){0.f,0.f,0.f,0.f};
      c = __builtin_amdgcn_mfma_f32_16x16x32_bf16(ka0, qb0, c, 0, 0, 0);
      c = __builtin_amdgcn_mfma_f32_16x16x32_bf16(ka1, qb1, c, 0, 0, 0);
      S[nt] = c;
    }

    // bias add (mask folded into bias: kg>256 -> -3e38) + row max
    float m = -3e38f;
    #pragma unroll
    for (int nt = 0; nt < 17; nt++){
      S[nt][0] += bflo(bu[nt].x); S[nt][1] += bfhi(bu[nt].x);
      S[nt][2] += bflo(bu[nt].y); S[nt][3] += bfhi(bu[nt].y);
      m = fmaxf(m, fmaxf(fmaxf(S[nt][0], S[nt][1]), fmaxf(S[nt][2], S[nt][3])));
    }
    m = fmaxf(m, __shfl_xor(m, 16, 64));
    m = fmaxf(m, __shfl_xor(m, 32, 64));

    // exp + pack to bf16 pairs + row sum
    float lsum = 0.f;
    uint32_t pklo[17], pkhi[17];
    #pragma unroll
    for (int nt = 0; nt < 17; nt++){
      float p0 = __expf(S[nt][0] - m), p1 = __expf(S[nt][1] - m);
      float p2 = __expf(S[nt][2] - m), p3 = __expf(S[nt][3] - m);
      lsum += (p0 + p1) + (p2 + p3);
      pklo[nt] = pack2(p0, p1); pkhi[nt] = pack2(p2, p3);
    }
    lsum += __shfl_xor(lsum, 16, 64);
    lsum += __shfl_xor(lsum, 32, 64);

    // PV: build P a-frags via quad shuffles, accumulate O[q][d]
    floatx4 o[4];
    #pragma unroll
    for (int dt = 0; dt < 4; dt++) o[dt] = (floatx4){0.f,0.f,0.f,0.f};
    #pragma unroll
    for (int ks = 0; ks < 9; ks++){
      uint32_t t0[4], t1[4];
      t0[0] = (uint32_t)__shfl((int)pklo[2*ks], srcA, 64);
      t0[1] = (uint32_t)__shfl((int)pkhi[2*ks], srcA, 64);
      t0[2] = (uint32_t)__shfl((int)pklo[2*ks], srcB, 64);
      t0[3] = (uint32_t)__shfl((int)pkhi[2*ks], srcB, 64);
      if (2*ks + 1 <= 16){
        t1[0] = (uint32_t)__shfl((int)pklo[2*ks+1], srcA, 64);
        t1[1] = (uint32_t)__shfl((int)pkhi[2*ks+1], srcA, 64);
        t1[2] = (uint32_t)__shfl((int)pklo[2*ks+1], srcB, 64);
        t1[3] = (uint32_t)__shfl((int)pkhi[2*ks+1], srcB, 64);
      } else {
        t1[0] = 0; t1[1] = 0; t1[2] = 0; t1[3] = 0;
      }
      union { uint32_t u[4]; bf16x8 v; } pa;
      bool lowhalf = (quad < 2);
      pa.u[0] = lowhalf ? t0[0] : t1[0];
      pa.u[1] = lowhalf ? t0[1] : t1[1];
      pa.u[2] = lowhalf ? t0[2] : t1[2];
      pa.u[3] = lowhalf ? t0[3] : t1[3];
      #pragma unroll
      for (int dt = 0; dt < 4; dt++){
        bf16x8 vb = *(const bf16x8*)&Vt[(dt*16 + l16)*VS + ks*32 + quad*8];
        o[dt] = __builtin_amdgcn_mfma_f32_16x16x32_bf16(pa.v, vb, o[dt], 0, 0, 0);
      }
    }

    // epilogue: normalize -> per-wave LDS tile -> coalesced uint4 stores
    #pragma unroll
    for (int r = 0; r < 4; r++){
      int qr = quad*4 + r;
      float ls = __shfl(lsum, qr, 64);
      float rinv = 1.0f / ls;
      #pragma unroll
      for (int dt = 0; dt < 4; dt++)
        Os[wave][qr*72 + dt*16 + l16] = (bf16)(o[dt][r] * rinv);
    }
    // wave-private buffer: no barrier needed; compiler orders the LDS ops
    #pragma unroll
    for (int half = 0; half < 2; half++){
      int rowL = (lane >> 3) + half*8;            // 0..15
      int chunk = lane & 7;                        // 8 x 16B = 128B per row
      int q = q0 + rowL;
      uint4 ov = *(const uint4*)&Os[wave][rowL*72 + chunk*8];
      if (q <= 256) *(uint4*)&AO[aoBase + (size_t)q*1024 + chunk*8] = ov;
    }
  }
}

extern "C" void kernel_launch(void* const* d_in, const int* in_sizes, int n_in,
                              void* d_out, int out_size, void* d_ws, size_t ws_size,
                              hipStream_t stream)
{
  (void)in_sizes; (void)n_in; (void)out_size; (void)ws_size;
  const float* x    = (const float*)d_in[0];
  const float* rc   = (const float*)d_in[1];
  const float* rsn  = (const float*)d_in[2];
  const float* q_w  = (const float*)d_in[3];
  const float* q_b  = (const float*)d_in[4];
  const float* k_w  = (const float*)d_in[5];
  const float* v_w  = (const float*)d_in[6];
  const float* v_b  = (const float*)d_in[7];
  const float* tab  = (const float*)d_in[8];
  const float* ig   = (const float*)d_in[9];
  const float* ib   = (const float*)d_in[10];
  const float* pw   = (const float*)d_in[11];
  const float* pb   = (const float*)d_in[12];
  const float* n1g  = (const float*)d_in[13];
  const float* n1b  = (const float*)d_in[14];
  const float* n2g  = (const float*)d_in[15];
  const float* n2b  = (const float*)d_in[16];
  const float* w1w  = (const float*)d_in[17];
  const float* w1b  = (const float*)d_in[18];
  const float* w2w  = (const float*)d_in[19];
  const float* w2b  = (const float*)d_in[20];
  const float* fg   = (const float*)d_in[21];
  const float* fb   = (const float*)d_in[22];
  const float* w3w  = (const float*)d_in[23];
  const float* w3b  = (const float*)d_in[24];

  const int M = 64 * 257;        // 16448
  const int D = 1024, HD = 4096;
  char* ws = (char*)d_ws;
  const size_t CHB = (size_t)M * D * 2;          // 33,685,504 B
  bf16* B0 = (bf16*)(ws);
  bf16* B1 = (bf16*)(ws + CHB);
  bf16* B2 = (bf16*)(ws + 2*CHB);
  bf16* B3 = (bf16*)(ws + 3*CHB);
  bf16* WQ = (bf16*)(ws + 4*CHB);
  bf16* WK = WQ + (size_t)D*D;
  bf16* WV = WK + (size_t)D*D;
  bf16* WP = WV + (size_t)D*D;
  bf16* W1 = WP + (size_t)D*D;
  bf16* W2 = W1 + (size_t)HD*D;
  bf16* W3 = W2 + (size_t)HD*D;
  float* QKVB = (float*)(W3 + (size_t)HD*D);
  bf16* XN  = B0;          // LN1 out
  bf16* QKV = B1;          // fused [M][3072] spans B1..B3
  bf16* AO  = B0;          // XN dead after QKV GEMM
  bf16* AOL = B1;          // QKV dead after attention
  bf16* X1  = B2;
  bf16* XN2 = B3;
  bf16* HS  = B0;          // spans B0+B1 during FFN
  bf16* biasB = (bf16*)d_out;   // 2.37 MB scratch in d_out; dead before FFN writes OUT
  float* OUT = (float*)d_out;

  dim3 blk(256);
  dim3 g1(D/128, (M + 127)/128);
  dim3 gqkv(3072/128, (M + 127)/128);

  const int n8_D = D*D/8;      // 131072
  const int n8_H = HD*D/8;     // 524288
  cvt_kernel<<<dim3(n8_D/256), blk, 0, stream>>>(q_w, WQ, n8_D, 0.125f);  // fold attn scale into Q
  cvt_kernel<<<dim3(n8_D/256), blk, 0, stream>>>(k_w, WK, n8_D, 1.f);
  cvt_kernel<<<dim3(n8_D/256), blk, 0, stream>>>(v_w, WV, n8_D, 1.f);
  cvt_kernel<<<dim3(n8_D/256), blk, 0, stream>>>(pw,  WP, n8_D, 1.f);
  cvt_kernel<<<dim3(n8_H/256), blk, 0, stream>>>(w1w, W1, n8_H, 1.f);
  cvt_kernel<<<dim3(n8_H/256), blk, 0, stream>>>(w2w, W2, n8_H, 1.f);
  cvt_kernel<<<dim3(n8_H/256), blk, 0, stream>>>(w3w, W3, n8_H, 1.f);
  qkvb_fill<<<dim3(12), blk, 0, stream>>>(q_b, v_b, QKVB);
  bias_fill<<<dim3((16*272*272 + 255)/256), blk, 0, stream>>>(tab, biasB);

  ln_kernel<1024, float><<<dim3(M), blk, 0, stream>>>(x, n1g, n1b, XN, M);
  gemm_bt<bf16, bf16><<<gqkv, blk, 0, stream>>>(XN, WQ, QKVB, (const bf16*)nullptr, QKV, M, 3072, D, 0);
  rope_kernel<<<dim3(64*256*512/256), blk, 0, stream>>>(QKV, rc, rsn);
  attn_kernel<<<dim3(64*16), blk, 0, stream>>>(QKV, biasB, AO);
  ln_kernel<1024, bf16><<<dim3(M), blk, 0, stream>>>(AO, ig, ib, AOL, M);
  gemm_bt<float, bf16><<<g1, blk, 0, stream>>>(AOL, WP, pb, x, X1, M, D, D, 1);
  ln_kernel<1024, bf16><<<dim3(M), blk, 0, stream>>>(X1, n2g, n2b, XN2, M);

  const int MC = M / 2;                       // 8224
  dim3 g2(HD/128, (MC + 127)/128);
  dim3 g1c(D/128, (MC + 127)/128);
  for (int c = 0; c < 2; c++){
    const bf16* a2 = XN2 + (size_t)c * MC * D;
    const bf16* x1 = X1  + (size_t)c * MC * D;
    float*      oc = OUT + (size_t)c * MC * D;
    gemm_bt<bf16, bf16><<<g2, blk, 0, stream>>>(a2, W1, w1b, (const bf16*)nullptr, HS, MC, HD, D, 0);
    gemm_bt<bf16, bf16><<<g2, blk, 0, stream>>>(a2, W2, w2b, HS, HS, MC, HD, D, 2);
    ln_kernel<4096, bf16><<<dim3(MC), blk, 0, stream>>>(HS, fg, fb, HS, MC);
    gemm_bt<bf16, float><<<g1c, blk, 0, stream>>>(HS, W3, w3b, x1, oc, MC, D, HD, 1);
  }
}